// Round 13
// baseline (896.830 us; speedup 1.0000x reference)
//
#include <hip/hip_runtime.h>
#include <math.h>

// Problem constants (fixed by reference setup_inputs)
#define B_ 16
#define C_ 512
#define N_ 4096   // 64*64
#define K_ 64

// Workspace layout (float offsets). Total ~689K floats = 2.76 MB.
#define OFF_PBIG    0         // [16 chunk][16 kstep][2 kh][64 lane] uint4 = 512 KB
#define OFF_INVSIG  131072    // [K][C] 1/sigma fp32
#define OFF_WSUM    163840    // [B][K]
#define OFF_GSUM    164864    // [B]
#define OFF_WX      164992    // [B][K][C] fp32, atomic-accumulated by k_agg

typedef short bf16x8 __attribute__((ext_vector_type(8)));   // 8 bf16 in 4 VGPRs
typedef float f32x16 __attribute__((ext_vector_type(16)));  // MFMA 32x32 accumulator

union U4 { uint4 u; bf16x8 b; };

__device__ __forceinline__ unsigned hi16(float f) { return __float_as_uint(f) >> 16; }
__device__ __forceinline__ unsigned hi16rne(float f) {
  return (__float_as_uint(f) + 0x8000u) >> 16;
}
__device__ __forceinline__ float fromhi(unsigned h) { return __uint_as_float(h << 16); }
// pack two floats' truncated-bf16 into one dword: low16 = bf16(lo), high16 = bf16(hi)
__device__ __forceinline__ unsigned pk(float lo, float hi) {
  return (__float_as_uint(lo) >> 16) | (__float_as_uint(hi) & 0xFFFF0000u);
}

// ---------------------------------------------------------------- kernel 1
// Build pbig (MFMA-fragment order), invsig; zero wsum/gsum/wx. One block per k.
// pbig uint4 index for (k,c): chunk=c>>5, ks=(c&31)>>1, lh=c&1, kh=k>>5:
//   (((chunk*16+ks)*2+kh)*64 + lh*32 + (k&31))
__global__ void k_prep(const float* __restrict__ anchor,
                       const float* __restrict__ sraw,
                       unsigned* __restrict__ pbig,
                       float* __restrict__ invsig,
                       float* __restrict__ wsum,
                       float* __restrict__ gsum,
                       float* __restrict__ wx) {
  const int k = blockIdx.x;
  const int t = threadIdx.x;
  __shared__ float s_is2[C_], s_m[C_];
  __shared__ float red[4];
  float part = 0.f;
#pragma unroll
  for (int r = 0; r < 2; r++) {
    int c = r * 256 + t;
    float a = anchor[k * C_ + c];
    float sg = 1.f / (1.f + __expf(-sraw[k * C_ + c]));
    float is = 1.f / sg;
    float is2 = is * is;
    s_is2[c] = is2;
    s_m[c] = -2.f * a * is2;
    invsig[k * C_ + c] = is;
    part = fmaf(a * a, is2, part);
  }
  float v = part;
#pragma unroll
  for (int off = 32; off; off >>= 1) v += __shfl_down(v, off);
  if ((t & 63) == 0) red[t >> 6] = v;
  __syncthreads();
  float cst = red[0] + red[1] + red[2] + red[3];
  unsigned ch = hi16(cst);
  unsigned clr = hi16rne(cst - fromhi(ch));
#pragma unroll
  for (int r = 0; r < 2; r++) {
    int c = r * 256 + t;
    float is2 = s_is2[c], m = s_m[c];
    unsigned ih = hi16(is2);
    unsigned ilr = hi16rne(is2 - fromhi(ih));
    unsigned mh = hi16(m);
    unsigned mlr = hi16rne(m - fromhi(mh));
    int chunk = c >> 5, ks = (c & 31) >> 1, lh = c & 1;
    int kh = k >> 5;
    size_t dst = ((((size_t)chunk * 16 + ks) * 2 + kh) * 64 + lh * 32 + (k & 31)) * 4;
    pbig[dst + 0] = ih | (ilr << 16);
    pbig[dst + 1] = ih | (mh << 16);
    pbig[dst + 2] = mlr | (mh << 16);
    pbig[dst + 3] = (c == 0) ? (ch | (clr << 16)) : 0u;
  }
  // zero wx slice for this k-block: 8192 floats = 2048 float4
  float4 z4 = make_float4(0.f, 0.f, 0.f, 0.f);
  float4* wz = (float4*)(wx + (size_t)k * 8192);
#pragma unroll
  for (int it = 0; it < 8; it++) wz[it * 256 + t] = z4;
  if (k == 0) {
    for (int i = t; i < B_ * K_; i += 256) wsum[i] = 0.f;
    if (t < B_) gsum[t] = 0.f;
  }
}

// ---------------------------------------------------------------- kernel 2
// MFMA distance GEMM (split-bf16, inner dim 4096) + softmax.
// v11 = v6 (83.6 us verified) + x-prefetch deepened to 2 CHUNKS AHEAD via a
// 4-buffer static rotation (x0..x3). Rationale: round-12 counters show
// hbm_gbps == hbm_bytes/dur == 1.05 TB/s (17% of achievable) with all pipes
// <30% -- concurrency-limited. 1-chunk-deep prefetch gives ~1100cy
// prefetch->use distance vs ~900cy HBM latency (zero slack); 2-deep gives
// ~2200cy and 2x x-bytes in flight. A-frags stay 1-deep (L2, short latency).
// Static VGPR ~224 < 256 cap of (256,2) -- occupancy unchanged.
__global__ __launch_bounds__(256, 2) void k_dist(
    const float* __restrict__ x,
    const unsigned* __restrict__ pbig,
    float* __restrict__ soft,
    float* __restrict__ wsum) {
  const int bid = blockIdx.x;
  const int swz = (bid & 7) * 64 + (bid >> 3);   // XCD-contiguous remap (512%8==0)
  const int b = swz >> 5;                        // 16 batches
  const int nblk = (swz & 31) * 128;             // 32 n-blocks of 128
  const int tid = threadIdx.x;
  const int wid = tid >> 6;
  const int lane = tid & 63;
  const int l31 = lane & 31;
  const int lh = lane >> 5;
  const int kh = wid & 1;                        // this wave's k-half
  const int n0 = nblk + (wid >> 1) * 64;         // wave's 64 n-columns

  __shared__ float cmax[4][2][32];
  __shared__ float csum[4][2][32];

  f32x16 accA, accB;
#pragma unroll
  for (int i = 0; i < 16; i++) { accA[i] = 0.f; accB[i] = 0.f; }

  const float* xcol0 = x + (size_t)b * (C_ * N_) + n0 + l31;
  const float* xcol1 = xcol0 + 32;
  const uint4* pf = (const uint4*)pbig + (size_t)kh * 64 + lane;

#define PACKMF(XV, CC, ACC, AFRAG)                                            \
  {                                                                           \
    float xv = (XV);                                                          \
    float x2 = xv * xv;                                                       \
    unsigned u = __float_as_uint(xv);                                         \
    unsigned u2 = __float_as_uint(x2);                                        \
    unsigned uhf = u & 0xFFFF0000u;                                           \
    unsigned u2hf = u2 & 0xFFFF0000u;                                         \
    float xl = xv - __uint_as_float(uhf);                                     \
    float x2l = x2 - __uint_as_float(u2hf);                                   \
    U4 bf;                                                                    \
    bf.u.x = (u2 >> 16) | u2hf;                                               \
    bf.u.y = ((__float_as_uint(x2l) + 0x8000u) >> 16) | uhf;                  \
    bf.u.z = (u >> 16) | ((__float_as_uint(xl) + 0x8000u) & 0xFFFF0000u);     \
    bf.u.w = ((CC) == 0) ? 0x3F803F80u : 0u;                                  \
    ACC = __builtin_amdgcn_mfma_f32_32x32x16_bf16((AFRAG), bf.b, ACC, 0, 0, 0); \
  }

// One chunk: prefetch x for chunk+2 into PXA/PXB (if DO_PX), A-frags for
// chunk+1 into FNXT (if DO_PA), then 16 ksteps consuming XA/XB + FCUR.
#define CHUNKQ(C, FCUR, FNXT, XA, XB, PXA, PXB, DO_PX, DO_PA)                 \
  {                                                                           \
    const int chunk_ = (C);                                                   \
    if (DO_PX) {                                                              \
      _Pragma("unroll")                                                       \
      for (int kk = 0; kk < 16; kk++) {                                       \
        PXA[kk] = xcol0[(size_t)((chunk_ + 2) * 32 + kk * 2 + lh) * N_];      \
        PXB[kk] = xcol1[(size_t)((chunk_ + 2) * 32 + kk * 2 + lh) * N_];      \
      }                                                                       \
    }                                                                         \
    if (DO_PA) {                                                              \
      _Pragma("unroll")                                                       \
      for (int kk = 0; kk < 16; kk++)                                         \
        FNXT[kk].u = pf[(size_t)((chunk_ + 1) * 16 + kk) * 128];              \
    }                                                                         \
    _Pragma("unroll")                                                         \
    for (int ks = 0; ks < 16; ks++) {                                         \
      const int c = chunk_ * 32 + ks * 2 + lh;                                \
      PACKMF(XA[ks], c, accA, FCUR[ks].b);                                    \
      PACKMF(XB[ks], c, accB, FCUR[ks].b);                                    \
    }                                                                         \
  }

  U4 f0_[16], f1_[16];
  float x0a[16], x0b[16], x1a[16], x1b[16];
  float x2a[16], x2b[16], x3a[16], x3b[16];
  // prologue: x for chunks 0,1; A-frags for chunk 0
#pragma unroll
  for (int kk = 0; kk < 16; kk++) {
    x0a[kk] = xcol0[(size_t)(kk * 2 + lh) * N_];
    x0b[kk] = xcol1[(size_t)(kk * 2 + lh) * N_];
    x1a[kk] = xcol0[(size_t)(32 + kk * 2 + lh) * N_];
    x1b[kk] = xcol1[(size_t)(32 + kk * 2 + lh) * N_];
    f0_[kk].u = pf[(size_t)kk * 128];
  }
  for (int j = 0; j < 4; j++) {
    CHUNKQ(4 * j + 0, f0_, f1_, x0a, x0b, x2a, x2b, 1, 1);
    CHUNKQ(4 * j + 1, f1_, f0_, x1a, x1b, x3a, x3b, 1, 1);
    CHUNKQ(4 * j + 2, f0_, f1_, x2a, x2b, x0a, x0b, (j < 3), 1);
    CHUNKQ(4 * j + 3, f1_, f0_, x3a, x3b, x1a, x1b, (j < 3), (j < 3));
  }
#undef CHUNKQ
#undef PACKMF

  // ---- softmax over k=64: in-wave (rows via lane^32) then cross-wave
  // (k-half partner wid^1) via tiny LDS max/sum arrays. Two n-columns. ----
  float* softb = soft + (size_t)b * (K_ * N_);
  float mA = -3.4e38f, mB = -3.4e38f;
#pragma unroll
  for (int r = 0; r < 16; r++) {
    accA[r] *= -0.5f; mA = fmaxf(mA, accA[r]);
    accB[r] *= -0.5f; mB = fmaxf(mB, accB[r]);
  }
  mA = fmaxf(mA, __shfl_xor(mA, 32));
  mB = fmaxf(mB, __shfl_xor(mB, 32));
  cmax[wid][0][l31] = mA;
  cmax[wid][1][l31] = mB;
  __syncthreads();
  mA = fmaxf(cmax[wid][0][l31], cmax[wid ^ 1][0][l31]);
  mB = fmaxf(cmax[wid][1][l31], cmax[wid ^ 1][1][l31]);
  float sA = 0.f, sB = 0.f;
#pragma unroll
  for (int r = 0; r < 16; r++) {
    accA[r] = __expf(accA[r] - mA); sA += accA[r];
    accB[r] = __expf(accB[r] - mB); sB += accB[r];
  }
  sA += __shfl_xor(sA, 32);
  sB += __shfl_xor(sB, 32);
  csum[wid][0][l31] = sA;
  csum[wid][1][l31] = sB;
  __syncthreads();
  float invA = 1.f / (csum[wid][0][l31] + csum[wid ^ 1][0][l31]);
  float invB = 1.f / (csum[wid][1][l31] + csum[wid ^ 1][1][l31]);
  const int nc0 = n0 + l31;
#pragma unroll
  for (int r = 0; r < 16; r++) {
    int k0 = kh * 32 + (r & 3) + 8 * (r >> 2) + 4 * lh;
    float wA = accA[r] * invA; accA[r] = wA;
    softb[(size_t)k0 * N_ + nc0] = wA;
    float wB = accB[r] * invB; accB[r] = wB;
    softb[(size_t)k0 * N_ + nc0 + 32] = wB;
  }
  // ---- wsum: both columns belong to b; reduce over 32 lanes, one atomic ----
#pragma unroll
  for (int r = 0; r < 16; r++) {
    float v = accA[r] + accB[r];
    v += __shfl_xor(v, 1);
    v += __shfl_xor(v, 2);
    v += __shfl_xor(v, 4);
    v += __shfl_xor(v, 8);
    v += __shfl_xor(v, 16);
    if (l31 == 0) {
      int k0 = kh * 32 + (r & 3) + 8 * (r >> 2) + 4 * lh;
      atomicAdd(&wsum[b * K_ + k0], v);
    }
  }
}

// ---------------------------------------------------------------- kernel 3
// Aggregation GEMM via MFMA: wx[b,k,c] += sum_n soft[b,k,n]*x[b,c,n].
// Explicit named register double-buffer (fA/fB, 6 float4 each, all-static).
// launch_bounds(256,3); grid 1024 (z=4), XCD-group swizzle, atomicAdd wx.
// (round-12 verified; r12 showed this k_agg == r8's in total time)
__global__ __launch_bounds__(256, 3) void k_agg(const float* __restrict__ x,
                                                const float* __restrict__ soft,
                                                float* __restrict__ wx) {
  const int bid = blockIdx.x;
  const int xcd = bid & 7, slot = bid >> 3;      // 128 slots per XCD
  const int grp = (slot >> 4) * 8 + xcd;         // 0..63 = (b,z) group
  const int ct = slot & 15;
  const int b = grp & 15, z = grp >> 4;
  const int tid = threadIdx.x;
  const int wid = tid >> 6, lane = tid & 63, l31 = lane & 31, lh = lane >> 5;
  const int c0 = ct * 32;
  const int n0 = z * 1024 + wid * 256;
  __shared__ float red[4][64][36];  // stride 36 floats (odd x16B) per lane

  f32x16 acc[2];
#pragma unroll
  for (int kt = 0; kt < 2; kt++)
#pragma unroll
    for (int i = 0; i < 16; i++) acc[kt][i] = 0.f;

  const float* sb = soft + (size_t)b * (K_ * N_);
  const float* xr = x + (size_t)b * (C_ * N_) + (size_t)(c0 + l31) * N_;
  const float* s0 = sb + (size_t)l31 * N_;
  const float* s1 = sb + (size_t)(32 + l31) * N_;

#define LOADK(DST, KS)                                                        \
  {                                                                           \
    int nb = n0 + (KS) * 16 + lh * 8;                                         \
    DST[0] = *(const float4*)&s0[nb];                                         \
    DST[1] = *(const float4*)&s0[nb + 4];                                     \
    DST[2] = *(const float4*)&s1[nb];                                         \
    DST[3] = *(const float4*)&s1[nb + 4];                                     \
    DST[4] = *(const float4*)&xr[nb];                                         \
    DST[5] = *(const float4*)&xr[nb + 4];                                     \
  }
#define COMPK(SRC)                                                            \
  {                                                                           \
    U4 A0, A1, Bf;                                                            \
    A0.u.x = pk(SRC[0].x, SRC[0].y); A0.u.y = pk(SRC[0].z, SRC[0].w);         \
    A0.u.z = pk(SRC[1].x, SRC[1].y); A0.u.w = pk(SRC[1].z, SRC[1].w);         \
    A1.u.x = pk(SRC[2].x, SRC[2].y); A1.u.y = pk(SRC[2].z, SRC[2].w);         \
    A1.u.z = pk(SRC[3].x, SRC[3].y); A1.u.w = pk(SRC[3].z, SRC[3].w);         \
    Bf.u.x = pk(SRC[4].x, SRC[4].y); Bf.u.y = pk(SRC[4].z, SRC[4].w);         \
    Bf.u.z = pk(SRC[5].x, SRC[5].y); Bf.u.w = pk(SRC[5].z, SRC[5].w);         \
    acc[0] = __builtin_amdgcn_mfma_f32_32x32x16_bf16(A0.b, Bf.b, acc[0], 0, 0, 0); \
    acc[1] = __builtin_amdgcn_mfma_f32_32x32x16_bf16(A1.b, Bf.b, acc[1], 0, 0, 0); \
  }

  float4 fA[6], fB[6];
  LOADK(fA, 0);
  for (int k2 = 0; k2 < 8; k2++) {
    LOADK(fB, 2 * k2 + 1);
    COMPK(fA);
    if (k2 < 7) LOADK(fA, 2 * k2 + 2);
    COMPK(fB);
  }
#undef LOADK
#undef COMPK

  // stash per-wave partials
#pragma unroll
  for (int kt = 0; kt < 2; kt++)
#pragma unroll
    for (int q = 0; q < 4; q++) {
      float4 vv = make_float4(acc[kt][q * 4], acc[kt][q * 4 + 1],
                              acc[kt][q * 4 + 2], acc[kt][q * 4 + 3]);
      *(float4*)&red[wid][lane][kt * 16 + q * 4] = vv;
    }
  __syncthreads();
  // cross-wave reduce + atomic accumulate (2048 outputs, 8 per thread)
  const int lt = tid & 63, sb4 = (tid >> 6) * 8;
  float v[8];
#pragma unroll
  for (int i = 0; i < 8; i++) v[i] = 0.f;
#pragma unroll
  for (int w = 0; w < 4; w++)
#pragma unroll
    for (int i = 0; i < 8; i++) v[i] += red[w][lt][sb4 + i];
#pragma unroll
  for (int i = 0; i < 8; i++) {
    int s = sb4 + i;
    int kt = s >> 4, r = s & 15;
    int k = kt * 32 + (r & 3) + 8 * (r >> 2) + 4 * (lt >> 5);
    atomicAdd(&wx[((size_t)b * K_ + k) * C_ + c0 + (lt & 31)], v[i]);
  }
}

// ---------------------------------------------------------------- kernel 4
// nodes = (wx - wsum*anchor)/sigma/(wsum+eps); intra L2-norm -> out0; gsum.
__global__ void k_nodes(const float* __restrict__ wx,
                        const float* __restrict__ wsum,
                        const float* __restrict__ anchor,
                        const float* __restrict__ invsig,
                        float* __restrict__ out0,
                        float* __restrict__ gsum) {
  const int k = blockIdx.x, b = blockIdx.y;
  const int tid = threadIdx.x;
  float wsv = wsum[b * K_ + k];
  float winv = 1.f / (wsv + 1e-9f);
  float vals[4];
  float local = 0.f;
#pragma unroll
  for (int r = 0; r < 4; r++) {
    int c = r * 128 + tid;
    float w = wx[((size_t)b * K_ + k) * C_ + c];
    float v = (w - wsv * anchor[k * C_ + c]) * invsig[k * C_ + c] * winv;
    vals[r] = v;
    local = fmaf(v, v, local);
  }
  float v = local;
#pragma unroll
  for (int off = 32; off; off >>= 1) v += __shfl_down(v, off);
  __shared__ float red[2];
  if ((tid & 63) == 0) red[tid >> 6] = v;
  __syncthreads();
  float sumsq = red[0] + red[1];
  float norm = sqrtf(sumsq);
  float scale = 1.f / fmaxf(norm, 1e-12f);
#pragma unroll
  for (int r = 0; r < 4; r++) {
    int c = r * 128 + tid;
    out0[((size_t)b * K_ + k) * C_ + c] = vals[r] * scale;
  }
  if (tid == 0) atomicAdd(&gsum[b], sumsq * scale * scale);
}

// ---------------------------------------------------------------- kernel 5
// Global L2 scale in place on out0 ([B][K*C] flat == reference (B,C,K)).
__global__ void k_final(float* __restrict__ out0,
                        const float* __restrict__ gsum) {
  for (int i = blockIdx.x * 256 + threadIdx.x; i < B_ * K_ * C_;
       i += gridDim.x * 256) {
    int b = i >> 15;  // K_*C_ = 32768
    out0[i] = out0[i] * (1.f / fmaxf(sqrtf(gsum[b]), 1e-12f));
  }
}

// ---------------------------------------------------------------- launch
extern "C" void kernel_launch(void* const* d_in, const int* in_sizes, int n_in,
                              void* d_out, int out_size, void* d_ws, size_t ws_size,
                              hipStream_t stream) {
  const float* x = (const float*)d_in[0];       // [B,C,H,W]
  const float* anchor = (const float*)d_in[1];  // [K,C]
  const float* sraw = (const float*)d_in[2];    // [K,C]
  float* out0 = (float*)d_out;                          // [B,C,K] flat
  float* soft = out0 + (size_t)B_ * C_ * K_;            // [B,K,N] (output 1)
  float* ws = (float*)d_ws;

  unsigned* pbig = (unsigned*)(ws + OFF_PBIG);
  float* invsig = ws + OFF_INVSIG;
  float* wsum = ws + OFF_WSUM;
  float* gsum = ws + OFF_GSUM;
  float* wx = ws + OFF_WX;

  k_prep<<<K_, 256, 0, stream>>>(anchor, sraw, pbig, invsig, wsum, gsum, wx);
  k_dist<<<512, 256, 0, stream>>>(x, pbig, soft, wsum);
  k_agg<<<1024, 256, 0, stream>>>(x, soft, wx);
  k_nodes<<<dim3(K_, B_), 128, 0, stream>>>(wx, wsum, anchor, invsig, out0,
                                            gsum);
  k_final<<<512, 256, 0, stream>>>(out0, gsum);
}

// Round 14
// 291.767 us; speedup vs baseline: 3.0738x; 3.0738x over previous
//
#include <hip/hip_runtime.h>
#include <math.h>

// Problem constants (fixed by reference setup_inputs)
#define B_ 16
#define C_ 512
#define N_ 4096   // 64*64
#define K_ 64

// Workspace layout (float offsets). Total ~689K floats = 2.76 MB.
#define OFF_PBIG    0         // [16 chunk][16 kstep][2 kh][64 lane] uint4 = 512 KB
#define OFF_INVSIG  131072    // [K][C] 1/sigma fp32
#define OFF_WSUM    163840    // [B][K]
#define OFF_GSUM    164864    // [B]
#define OFF_WX      164992    // [B][K][C] fp32, atomic-accumulated by k_agg

typedef short bf16x8 __attribute__((ext_vector_type(8)));   // 8 bf16 in 4 VGPRs
typedef float f32x16 __attribute__((ext_vector_type(16)));  // MFMA 32x32 accumulator

union U4 { uint4 u; bf16x8 b; };

__device__ __forceinline__ unsigned hi16(float f) { return __float_as_uint(f) >> 16; }
__device__ __forceinline__ unsigned hi16rne(float f) {
  return (__float_as_uint(f) + 0x8000u) >> 16;
}
__device__ __forceinline__ float fromhi(unsigned h) { return __uint_as_float(h << 16); }
// pack two floats' truncated-bf16 into one dword: low16 = bf16(lo), high16 = bf16(hi)
__device__ __forceinline__ unsigned pk(float lo, float hi) {
  return (__float_as_uint(lo) >> 16) | (__float_as_uint(hi) & 0xFFFF0000u);
}

// ---------------------------------------------------------------- kernel 1
// Build pbig (MFMA-fragment order), invsig; zero wsum/gsum/wx. One block per k.
// pbig uint4 index for (k,c): chunk=c>>5, ks=(c&31)>>1, lh=c&1, kh=k>>5:
//   (((chunk*16+ks)*2+kh)*64 + lh*32 + (k&31))
__global__ void k_prep(const float* __restrict__ anchor,
                       const float* __restrict__ sraw,
                       unsigned* __restrict__ pbig,
                       float* __restrict__ invsig,
                       float* __restrict__ wsum,
                       float* __restrict__ gsum,
                       float* __restrict__ wx) {
  const int k = blockIdx.x;
  const int t = threadIdx.x;
  __shared__ float s_is2[C_], s_m[C_];
  __shared__ float red[4];
  float part = 0.f;
#pragma unroll
  for (int r = 0; r < 2; r++) {
    int c = r * 256 + t;
    float a = anchor[k * C_ + c];
    float sg = 1.f / (1.f + __expf(-sraw[k * C_ + c]));
    float is = 1.f / sg;
    float is2 = is * is;
    s_is2[c] = is2;
    s_m[c] = -2.f * a * is2;
    invsig[k * C_ + c] = is;
    part = fmaf(a * a, is2, part);
  }
  float v = part;
#pragma unroll
  for (int off = 32; off; off >>= 1) v += __shfl_down(v, off);
  if ((t & 63) == 0) red[t >> 6] = v;
  __syncthreads();
  float cst = red[0] + red[1] + red[2] + red[3];
  unsigned ch = hi16(cst);
  unsigned clr = hi16rne(cst - fromhi(ch));
#pragma unroll
  for (int r = 0; r < 2; r++) {
    int c = r * 256 + t;
    float is2 = s_is2[c], m = s_m[c];
    unsigned ih = hi16(is2);
    unsigned ilr = hi16rne(is2 - fromhi(ih));
    unsigned mh = hi16(m);
    unsigned mlr = hi16rne(m - fromhi(mh));
    int chunk = c >> 5, ks = (c & 31) >> 1, lh = c & 1;
    int kh = k >> 5;
    size_t dst = ((((size_t)chunk * 16 + ks) * 2 + kh) * 64 + lh * 32 + (k & 31)) * 4;
    pbig[dst + 0] = ih | (ilr << 16);
    pbig[dst + 1] = ih | (mh << 16);
    pbig[dst + 2] = mlr | (mh << 16);
    pbig[dst + 3] = (c == 0) ? (ch | (clr << 16)) : 0u;
  }
  // zero wx slice for this k-block: 8192 floats = 2048 float4
  float4 z4 = make_float4(0.f, 0.f, 0.f, 0.f);
  float4* wz = (float4*)(wx + (size_t)k * 8192);
#pragma unroll
  for (int it = 0; it < 8; it++) wz[it * 256 + t] = z4;
  if (k == 0) {
    for (int i = t; i < B_ * K_; i += 256) wsum[i] = 0.f;
    if (t < B_) gsum[t] = 0.f;
  }
}

// ---------------------------------------------------------------- kernel 2
// MFMA distance GEMM (split-bf16, inner dim 4096) + softmax.
// v6 VERBATIM (measured 83.6 us, rounds 8 & 12): explicit register pipeline.
// Wave tile 32k x 64n: each A-fragment feeds TWO MFMA chains (accA/accB).
// A-frags AND x double-buffered in named register arrays (all-static
// indices) so 48 loads are in flight while the current chunk computes.
// Grid 512 (XCD-swizzled), 4 waves/block, launch_bounds(256,2).
// NOTE (r9-r13): every deeper-concurrency variant (split-C r7/r8, LDS-staged
// x r9, 2-chunk x-prefetch r11) spilled or lost to barrier cost. The
// allocator's fixed point for this body is ~124 VGPR; do not exceed it.
__global__ __launch_bounds__(256, 2) void k_dist(
    const float* __restrict__ x,
    const unsigned* __restrict__ pbig,
    float* __restrict__ soft,
    float* __restrict__ wsum) {
  const int bid = blockIdx.x;
  const int swz = (bid & 7) * 64 + (bid >> 3);   // XCD-contiguous remap (512%8==0)
  const int b = swz >> 5;                        // 16 batches
  const int nblk = (swz & 31) * 128;             // 32 n-blocks of 128
  const int tid = threadIdx.x;
  const int wid = tid >> 6;
  const int lane = tid & 63;
  const int l31 = lane & 31;
  const int lh = lane >> 5;
  const int kh = wid & 1;                        // this wave's k-half
  const int n0 = nblk + (wid >> 1) * 64;         // wave's 64 n-columns

  __shared__ float cmax[4][2][32];
  __shared__ float csum[4][2][32];

  f32x16 accA, accB;
#pragma unroll
  for (int i = 0; i < 16; i++) { accA[i] = 0.f; accB[i] = 0.f; }

  const float* xcol0 = x + (size_t)b * (C_ * N_) + n0 + l31;
  const float* xcol1 = xcol0 + 32;
  const uint4* pf = (const uint4*)pbig + (size_t)kh * 64 + lane;

#define PACKMF(XV, CC, ACC, AFRAG)                                            \
  {                                                                           \
    float xv = (XV);                                                          \
    float x2 = xv * xv;                                                       \
    unsigned u = __float_as_uint(xv);                                         \
    unsigned u2 = __float_as_uint(x2);                                        \
    unsigned uhf = u & 0xFFFF0000u;                                           \
    unsigned u2hf = u2 & 0xFFFF0000u;                                         \
    float xl = xv - __uint_as_float(uhf);                                     \
    float x2l = x2 - __uint_as_float(u2hf);                                   \
    U4 bf;                                                                    \
    bf.u.x = (u2 >> 16) | u2hf;                                               \
    bf.u.y = ((__float_as_uint(x2l) + 0x8000u) >> 16) | uhf;                  \
    bf.u.z = (u >> 16) | ((__float_as_uint(xl) + 0x8000u) & 0xFFFF0000u);     \
    bf.u.w = ((CC) == 0) ? 0x3F803F80u : 0u;                                  \
    ACC = __builtin_amdgcn_mfma_f32_32x32x16_bf16((AFRAG), bf.b, ACC, 0, 0, 0); \
  }

// One chunk: optionally prefetch chunk+1 into FNXT/XN*, then 16 ksteps
// consuming FCUR/XC* (each A-frag feeds both acc chains).
#define CHUNK_BODY(CHUNK, FCUR, FNXT, XC0, XC1, XN0, XN1, PREFETCH)           \
  {                                                                           \
    const int chunk_ = (CHUNK);                                               \
    if (PREFETCH) {                                                           \
      _Pragma("unroll")                                                       \
      for (int kk = 0; kk < 16; kk++) {                                       \
        FNXT[kk].u = pf[(size_t)((chunk_ + 1) * 16 + kk) * 128];              \
        XN0[kk] = xcol0[(size_t)((chunk_ + 1) * 32 + kk * 2 + lh) * N_];      \
        XN1[kk] = xcol1[(size_t)((chunk_ + 1) * 32 + kk * 2 + lh) * N_];      \
      }                                                                       \
    }                                                                         \
    _Pragma("unroll")                                                         \
    for (int ks = 0; ks < 16; ks++) {                                         \
      const int c = chunk_ * 32 + ks * 2 + lh;                                \
      PACKMF(XC0[ks], c, accA, FCUR[ks].b);                                   \
      PACKMF(XC1[ks], c, accB, FCUR[ks].b);                                   \
    }                                                                         \
  }

  U4 f0_[16], f1_[16];
  float a0_[16], a1_[16], b0_[16], b1_[16];
#pragma unroll
  for (int kk = 0; kk < 16; kk++) {
    f0_[kk].u = pf[(size_t)kk * 128];
    a0_[kk] = xcol0[(size_t)(kk * 2 + lh) * N_];
    a1_[kk] = xcol1[(size_t)(kk * 2 + lh) * N_];
  }
  for (int c2 = 0; c2 < 8; c2++) {
    CHUNK_BODY(2 * c2,     f0_, f1_, a0_, a1_, b0_, b1_, 1);
    CHUNK_BODY(2 * c2 + 1, f1_, f0_, b0_, b1_, a0_, a1_, (c2 < 7));
  }
#undef CHUNK_BODY
#undef PACKMF

  // ---- softmax over k=64: in-wave (rows via lane^32) then cross-wave
  // (k-half partner wid^1) via tiny LDS max/sum arrays. Two n-columns. ----
  float* softb = soft + (size_t)b * (K_ * N_);
  float mA = -3.4e38f, mB = -3.4e38f;
#pragma unroll
  for (int r = 0; r < 16; r++) {
    accA[r] *= -0.5f; mA = fmaxf(mA, accA[r]);
    accB[r] *= -0.5f; mB = fmaxf(mB, accB[r]);
  }
  mA = fmaxf(mA, __shfl_xor(mA, 32));
  mB = fmaxf(mB, __shfl_xor(mB, 32));
  cmax[wid][0][l31] = mA;
  cmax[wid][1][l31] = mB;
  __syncthreads();
  mA = fmaxf(cmax[wid][0][l31], cmax[wid ^ 1][0][l31]);
  mB = fmaxf(cmax[wid][1][l31], cmax[wid ^ 1][1][l31]);
  float sA = 0.f, sB = 0.f;
#pragma unroll
  for (int r = 0; r < 16; r++) {
    accA[r] = __expf(accA[r] - mA); sA += accA[r];
    accB[r] = __expf(accB[r] - mB); sB += accB[r];
  }
  sA += __shfl_xor(sA, 32);
  sB += __shfl_xor(sB, 32);
  csum[wid][0][l31] = sA;
  csum[wid][1][l31] = sB;
  __syncthreads();
  float invA = 1.f / (csum[wid][0][l31] + csum[wid ^ 1][0][l31]);
  float invB = 1.f / (csum[wid][1][l31] + csum[wid ^ 1][1][l31]);
  const int nc0 = n0 + l31;
#pragma unroll
  for (int r = 0; r < 16; r++) {
    int k0 = kh * 32 + (r & 3) + 8 * (r >> 2) + 4 * lh;
    float wA = accA[r] * invA; accA[r] = wA;
    softb[(size_t)k0 * N_ + nc0] = wA;
    float wB = accB[r] * invB; accB[r] = wB;
    softb[(size_t)k0 * N_ + nc0 + 32] = wB;
  }
  // ---- wsum: both columns belong to b; reduce over 32 lanes, one atomic ----
#pragma unroll
  for (int r = 0; r < 16; r++) {
    float v = accA[r] + accB[r];
    v += __shfl_xor(v, 1);
    v += __shfl_xor(v, 2);
    v += __shfl_xor(v, 4);
    v += __shfl_xor(v, 8);
    v += __shfl_xor(v, 16);
    if (l31 == 0) {
      int k0 = kh * 32 + (r & 3) + 8 * (r >> 2) + 4 * lh;
      atomicAdd(&wsum[b * K_ + k0], v);
    }
  }
}

// ---------------------------------------------------------------- kernel 3
// Aggregation GEMM via MFMA: wx[b,k,c] += sum_n soft[b,k,n]*x[b,c,n].
// v12: z=8 (grid 2048, 8 blocks/CU supply) -- the one isolated change this
// round. Same register double-buffer (fA/fB) and epilogue as round 12;
// per-block ksteps halve to 8. launch_bounds(256,3).
__global__ __launch_bounds__(256, 3) void k_agg(const float* __restrict__ x,
                                                const float* __restrict__ soft,
                                                float* __restrict__ wx) {
  const int bid = blockIdx.x;
  const int xcd = bid & 7, slot = bid >> 3;      // 256 slots per XCD
  const int grp = (slot >> 4) * 8 + xcd;         // 0..127 = (b,z) group
  const int ct = slot & 15;
  const int b = grp & 15, z = grp >> 4;          // z 0..7
  const int tid = threadIdx.x;
  const int wid = tid >> 6, lane = tid & 63, l31 = lane & 31, lh = lane >> 5;
  const int c0 = ct * 32;
  const int n0 = z * 512 + wid * 128;
  __shared__ float red[4][64][36];  // stride 36 floats (odd x16B) per lane

  f32x16 acc[2];
#pragma unroll
  for (int kt = 0; kt < 2; kt++)
#pragma unroll
    for (int i = 0; i < 16; i++) acc[kt][i] = 0.f;

  const float* sb = soft + (size_t)b * (K_ * N_);
  const float* xr = x + (size_t)b * (C_ * N_) + (size_t)(c0 + l31) * N_;
  const float* s0 = sb + (size_t)l31 * N_;
  const float* s1 = sb + (size_t)(32 + l31) * N_;

#define LOADK(DST, KS)                                                        \
  {                                                                           \
    int nb = n0 + (KS) * 16 + lh * 8;                                         \
    DST[0] = *(const float4*)&s0[nb];                                         \
    DST[1] = *(const float4*)&s0[nb + 4];                                     \
    DST[2] = *(const float4*)&s1[nb];                                         \
    DST[3] = *(const float4*)&s1[nb + 4];                                     \
    DST[4] = *(const float4*)&xr[nb];                                         \
    DST[5] = *(const float4*)&xr[nb + 4];                                     \
  }
#define COMPK(SRC)                                                            \
  {                                                                           \
    U4 A0, A1, Bf;                                                            \
    A0.u.x = pk(SRC[0].x, SRC[0].y); A0.u.y = pk(SRC[0].z, SRC[0].w);         \
    A0.u.z = pk(SRC[1].x, SRC[1].y); A0.u.w = pk(SRC[1].z, SRC[1].w);         \
    A1.u.x = pk(SRC[2].x, SRC[2].y); A1.u.y = pk(SRC[2].z, SRC[2].w);         \
    A1.u.z = pk(SRC[3].x, SRC[3].y); A1.u.w = pk(SRC[3].z, SRC[3].w);         \
    Bf.u.x = pk(SRC[4].x, SRC[4].y); Bf.u.y = pk(SRC[4].z, SRC[4].w);         \
    Bf.u.z = pk(SRC[5].x, SRC[5].y); Bf.u.w = pk(SRC[5].z, SRC[5].w);         \
    acc[0] = __builtin_amdgcn_mfma_f32_32x32x16_bf16(A0.b, Bf.b, acc[0], 0, 0, 0); \
    acc[1] = __builtin_amdgcn_mfma_f32_32x32x16_bf16(A1.b, Bf.b, acc[1], 0, 0, 0); \
  }

  float4 fA[6], fB[6];
  LOADK(fA, 0);
  for (int k2 = 0; k2 < 4; k2++) {
    LOADK(fB, 2 * k2 + 1);
    COMPK(fA);
    if (k2 < 3) LOADK(fA, 2 * k2 + 2);
    COMPK(fB);
  }
#undef LOADK
#undef COMPK

  // stash per-wave partials
#pragma unroll
  for (int kt = 0; kt < 2; kt++)
#pragma unroll
    for (int q = 0; q < 4; q++) {
      float4 vv = make_float4(acc[kt][q * 4], acc[kt][q * 4 + 1],
                              acc[kt][q * 4 + 2], acc[kt][q * 4 + 3]);
      *(float4*)&red[wid][lane][kt * 16 + q * 4] = vv;
    }
  __syncthreads();
  // cross-wave reduce + atomic accumulate (2048 outputs, 8 per thread)
  const int lt = tid & 63, sb4 = (tid >> 6) * 8;
  float v[8];
#pragma unroll
  for (int i = 0; i < 8; i++) v[i] = 0.f;
#pragma unroll
  for (int w = 0; w < 4; w++)
#pragma unroll
    for (int i = 0; i < 8; i++) v[i] += red[w][lt][sb4 + i];
#pragma unroll
  for (int i = 0; i < 8; i++) {
    int s = sb4 + i;
    int kt = s >> 4, r = s & 15;
    int k = kt * 32 + (r & 3) + 8 * (r >> 2) + 4 * (lt >> 5);
    atomicAdd(&wx[((size_t)b * K_ + k) * C_ + c0 + (lt & 31)], v[i]);
  }
}

// ---------------------------------------------------------------- kernel 4
// nodes = (wx - wsum*anchor)/sigma/(wsum+eps); intra L2-norm -> out0; gsum.
__global__ void k_nodes(const float* __restrict__ wx,
                        const float* __restrict__ wsum,
                        const float* __restrict__ anchor,
                        const float* __restrict__ invsig,
                        float* __restrict__ out0,
                        float* __restrict__ gsum) {
  const int k = blockIdx.x, b = blockIdx.y;
  const int tid = threadIdx.x;
  float wsv = wsum[b * K_ + k];
  float winv = 1.f / (wsv + 1e-9f);
  float vals[4];
  float local = 0.f;
#pragma unroll
  for (int r = 0; r < 4; r++) {
    int c = r * 128 + tid;
    float w = wx[((size_t)b * K_ + k) * C_ + c];
    float v = (w - wsv * anchor[k * C_ + c]) * invsig[k * C_ + c] * winv;
    vals[r] = v;
    local = fmaf(v, v, local);
  }
  float v = local;
#pragma unroll
  for (int off = 32; off; off >>= 1) v += __shfl_down(v, off);
  __shared__ float red[2];
  if ((tid & 63) == 0) red[tid >> 6] = v;
  __syncthreads();
  float sumsq = red[0] + red[1];
  float norm = sqrtf(sumsq);
  float scale = 1.f / fmaxf(norm, 1e-12f);
#pragma unroll
  for (int r = 0; r < 4; r++) {
    int c = r * 128 + tid;
    out0[((size_t)b * K_ + k) * C_ + c] = vals[r] * scale;
  }
  if (tid == 0) atomicAdd(&gsum[b], sumsq * scale * scale);
}

// ---------------------------------------------------------------- kernel 5
// Global L2 scale in place on out0 ([B][K*C] flat == reference (B,C,K)).
__global__ void k_final(float* __restrict__ out0,
                        const float* __restrict__ gsum) {
  for (int i = blockIdx.x * 256 + threadIdx.x; i < B_ * K_ * C_;
       i += gridDim.x * 256) {
    int b = i >> 15;  // K_*C_ = 32768
    out0[i] = out0[i] * (1.f / fmaxf(sqrtf(gsum[b]), 1e-12f));
  }
}

// ---------------------------------------------------------------- launch
extern "C" void kernel_launch(void* const* d_in, const int* in_sizes, int n_in,
                              void* d_out, int out_size, void* d_ws, size_t ws_size,
                              hipStream_t stream) {
  const float* x = (const float*)d_in[0];       // [B,C,H,W]
  const float* anchor = (const float*)d_in[1];  // [K,C]
  const float* sraw = (const float*)d_in[2];    // [K,C]
  float* out0 = (float*)d_out;                          // [B,C,K] flat
  float* soft = out0 + (size_t)B_ * C_ * K_;            // [B,K,N] (output 1)
  float* ws = (float*)d_ws;

  unsigned* pbig = (unsigned*)(ws + OFF_PBIG);
  float* invsig = ws + OFF_INVSIG;
  float* wsum = ws + OFF_WSUM;
  float* gsum = ws + OFF_GSUM;
  float* wx = ws + OFF_WX;

  k_prep<<<K_, 256, 0, stream>>>(anchor, sraw, pbig, invsig, wsum, gsum, wx);
  k_dist<<<512, 256, 0, stream>>>(x, pbig, soft, wsum);
  k_agg<<<2048, 256, 0, stream>>>(x, soft, wx);
  k_nodes<<<dim3(K_, B_), 128, 0, stream>>>(wx, wsum, anchor, invsig, out0,
                                            gsum);
  k_final<<<512, 256, 0, stream>>>(out0, gsum);
}